// Round 6
// baseline (1260.513 us; speedup 1.0000x reference)
//
#include <hip/hip_runtime.h>
#include <math.h>

#define B 4
#define CIN 64
#define H 128
#define W 128
#define COUT 128
#define KK 9
#define HW (H*W)

#define OFFS_SZ (B*18*HW)
#define MASK_SZ (B*9*HW)
#define WTAP3_SZ (CIN*9*28)          // [c][tap][f(28, 27 real)]
#define WBF_COLS 640                 // 4 chunks x 160 (144 real + 16 zero)
#define WBF_SHORTS (COUT*WBF_COLS)
#define LDK 168                      // LDS k-stride (shorts); 336B row stride

typedef __attribute__((ext_vector_type(8))) short short8;
typedef __attribute__((ext_vector_type(4))) float f32x4;
typedef __attribute__((ext_vector_type(2))) float f32x2;
typedef f32x2 __attribute__((aligned(4))) f32x2a;   // align-4 float2 load

__device__ __forceinline__ unsigned short f2bf(float f) {
    unsigned int u = __float_as_uint(f);
    u += 0x7fffu + ((u >> 16) & 1u);
    return (unsigned short)(u >> 16);
}

// ---------------------------------------------------------------------------
// prep: wtap3[(c*9+tap)*28+f] (f-contiguous for wave-uniform scalar loads),
// bcat biases.
// ---------------------------------------------------------------------------
__global__ void prep_kernel(const float* __restrict__ w_off, const float* __restrict__ b_off,
                            const float* __restrict__ w_mask, const float* __restrict__ b_mask,
                            float* __restrict__ wtap3, float* __restrict__ bcat)
{
    int idx = blockIdx.x * 256 + threadIdx.x;
    if (idx < WTAP3_SZ) {
        int c   = idx / 252;
        int rem = idx % 252;
        int tap = rem / 28;
        int f   = rem % 28;
        float v = 0.f;
        if (f < 18)      v = w_off[(f * CIN + c) * 9 + tap];
        else if (f < 27) v = w_mask[((f - 18) * CIN + c) * 9 + tap];
        wtap3[idx] = v;
    }
    if (blockIdx.x == 0 && threadIdx.x < 32) {
        int f = threadIdx.x;
        float bv = 0.f;
        if (f < 18) bv = b_off[f];
        else if (f < 27) bv = b_mask[f - 18];
        bcat[f] = bv;
    }
}

// ---------------------------------------------------------------------------
// prep_wbf: einsum weights -> bf16, layout [o][cb*160 + tap*16 + ci];
// pad cols [144,160) per chunk are ZERO.
// ---------------------------------------------------------------------------
__global__ void prep_wbf(const float* __restrict__ wgt, short* __restrict__ wbf)
{
    int idx = blockIdx.x * 256 + threadIdx.x;
    if (idx >= WBF_SHORTS) return;
    int o  = idx / WBF_COLS;
    int kp = idx % WBF_COLS;
    int cb = kp / 160, r = kp % 160;
    float v = 0.f;
    if (r < 144) {
        int tap = r >> 4;
        int c   = cb * 16 + (r & 15);
        v = wgt[(o * CIN + c) * KK + tap];
    }
    wbf[idx] = (short)f2bf(v);
}

// ---------------------------------------------------------------------------
// XCD band swizzle (kept): T = (bid%8)*(n/8)+bid/8 gives each XCD a
// contiguous band of tiles -> window rows reused inside the local 4 MB L2.
// ---------------------------------------------------------------------------

// ---------------------------------------------------------------------------
// offmask2: lane = pixel, wave = 16-channel slice, acc[27] in registers.
// x read DIRECTLY from global (coalesced, L2-band resident, double-buffered);
// weights via wave-uniform address (scalar loads) from wtap3.
// DS traffic reduced to one 27 KB cross-wave reduction at the end.
// ---------------------------------------------------------------------------
__global__ __launch_bounds__(256, 4) void offmask2_kernel(
    const float* __restrict__ x, const float* __restrict__ wtap3,
    const float* __restrict__ bcat, float* __restrict__ offs,
    float* __restrict__ mask)
{
    const int bid = blockIdx.x;
    const int T = (bid & 7) * 128 + (bid >> 3);
    const int wo0 = (T & 1) * 64;
    const int ho  = (T >> 1) & 127;
    const int b   = T >> 8;
    const int tid = threadIdx.x;
    const int w   = tid >> 6;            // wave -> 16-channel slice
    const int px  = tid & 63;            // lane -> pixel
    const int wo  = wo0 + px;

    __shared__ float co4[4 * 27 * 64];   // 27,648 B partial sums

    float acc[27];
    #pragma unroll
    for (int f = 0; f < 27; ++f) acc[f] = 0.f;

    const float* xb = x + (size_t)b * CIN * HW;

    auto loadx = [&](int c, float* out) {
        const float* xc = xb + (size_t)c * HW;
        #pragma unroll
        for (int ky = 0; ky < 3; ++ky) {
            int y = ho - 1 + ky;
            bool vy = ((unsigned)y < (unsigned)H);
            #pragma unroll
            for (int kx = 0; kx < 3; ++kx) {
                int g = wo - 1 + kx;
                bool ok = vy && ((unsigned)g < (unsigned)W);
                out[ky * 3 + kx] = ok ? xc[y * W + g] : 0.f;
            }
        }
    };
    auto fma243 = [&](int c, const float* xv) {
        const float* wp = wtap3 + c * 252;   // wave-uniform address
        #pragma unroll
        for (int tap = 0; tap < 9; ++tap) {
            float xvt = xv[tap];
            #pragma unroll
            for (int f = 0; f < 27; ++f)
                acc[f] += wp[tap * 28 + f] * xvt;
        }
    };

    float xvA[9], xvB[9];
    loadx(w * 16, xvA);
    #pragma unroll 1
    for (int ci = 0; ci < 16; ci += 2) {
        loadx(w * 16 + ci + 1, xvB);
        fma243(w * 16 + ci, xvA);
        if (ci + 2 < 16) loadx(w * 16 + ci + 2, xvA);
        fma243(w * 16 + ci + 1, xvB);
    }

    // cross-wave reduction + bias/sigmoid + store
    #pragma unroll
    for (int f = 0; f < 27; ++f)
        co4[(w * 27 + f) * 64 + px] = acc[f];
    __syncthreads();
    #pragma unroll
    for (int i = 0; i < 7; ++i) {
        int idx = tid + i * 256;
        if (idx < 27 * 64) {
            float s = co4[idx] + co4[idx + 1728] + co4[idx + 2 * 1728]
                    + co4[idx + 3 * 1728];
            int f = idx >> 6, p = idx & 63;
            s += bcat[f];
            if (f < 18) {
                offs[((b * 18 + f) * H + ho) * W + wo0 + p] = s;
            } else {
                mask[((b * 9 + (f - 18)) * H + ho) * W + wo0 + p] =
                    1.f / (1.f + expf(-s));
            }
        }
    }
}

// ---------------------------------------------------------------------------
// deform5: LDS-window sampling with T14 async staging + chunk stagger.
// - window loads issued into REGISTERS one phase early (HBM latency hides
//   under sample/MFMA), ds_write after the barrier.
// - chunk processing order rotated by a per-block hash (accumulation is
//   order-independent) to decorrelate co-resident blocks' phases.
// LDS 35,328 B -> 4 blocks/CU.
// ---------------------------------------------------------------------------
__global__ __launch_bounds__(256, 4) void deform5_kernel(
    const float* __restrict__ x, const float* __restrict__ offs,
    const float* __restrict__ maskp, const short* __restrict__ wbf,
    float* __restrict__ out)
{
    const int bid = blockIdx.x;
    const int T = (bid & 7) * 128 + (bid >> 3);
    const int wo0 = (T & 1) * 64;
    const int ho  = (T >> 1) & 127;
    const int b   = T >> 8;
    const int tid  = threadIdx.x;
    const int lane = tid & 63;
    const int wv   = tid >> 6;
    const int oh   = (wv & 1) * 64;
    const int ph   = (wv >> 1) * 32;
    const int row16 = lane & 15, kq = lane >> 4;

    __shared__ __align__(16) float XW[8 * 6 * 72];    // 13,824 B
    __shared__ __align__(16) short S[64 * LDK];       // 21,504 B

    const float* xb = x + (size_t)b * CIN * HW;

    // ---- precompute per-thread staging slots (h-independent parts) ----
    int  st_lds[4]; int st_goff[4]; bool st_v[4], st_w[4];
    #pragma unroll
    for (int t = 0; t < 4; ++t) {
        int idx = tid + t * 256;
        st_w[t] = idx < 864;
        int ci = idx / 108, rem = idx % 108, row = rem / 18, q = rem % 18;
        int ys = min(max(ho - 2 + row, 0), H - 1);
        int g0 = wo0 - 4 + q * 4;
        st_lds[t]  = (ci * 6 + row) * 72 + q * 4;
        st_goff[t] = ci * HW + ys * W + g0;
        // window over-hangs are FULLY out of bounds (g0=-4 or 128) -> zeros
        st_v[t] = st_w[t] && (g0 >= 0) && (g0 <= W - 4);
    }
    f32x4 rg[4];
    auto regload = [&](int h) {
        const float* base = xb + (size_t)h * 8 * HW;
        #pragma unroll
        for (int t = 0; t < 4; ++t) {
            f32x4 v = {0.f, 0.f, 0.f, 0.f};
            if (st_v[t]) v = *(const f32x4*)(base + st_goff[t]);
            rg[t] = v;
        }
    };
    auto regwrite = [&]() {
        #pragma unroll
        for (int t = 0; t < 4; ++t)
            if (st_w[t]) *(f32x4*)&XW[st_lds[t]] = rg[t];
    };

    const int r0rot = (int)((unsigned)(bid * 2654435761u) >> 30);  // 0..3

    regload(2 * r0rot);    // first window's loads in flight under metadata

    // ---- metadata: slot s = tid + j*256 -> (tap k = s>>6, px p = s&63) ----
    int   moff[3][2];
    int   lidx0[3], lidx1[3];
    float wA0[3], wB0[3], wA1[3], wB1[3];
    #pragma unroll
    for (int j = 0; j < 3; ++j) {
        moff[j][0] = 0; moff[j][1] = 0;
        lidx0[j] = -1; lidx1[j] = 0;
        wA0[j] = 0.f; wB0[j] = 0.f; wA1[j] = 0.f; wB1[j] = 0.f;
        int s = tid + j * 256;
        if (s < 576) {
            int k = s >> 6, p = s & 63;
            int wo = wo0 + p;
            int ky = k / 3, kx = k % 3;
            int obase = ((b * 18 + 2 * k) * H + ho) * W + wo;
            float dy = offs[obase];
            float dx = offs[obase + HW];
            float mk = maskp[((b * 9 + k) * H + ho) * W + wo];
            float py  = (float)(ho - 1 + ky) + dy;
            float pxf = (float)(wo - 1 + kx) + dx;
            float fy = floorf(py), fx = floorf(pxf);
            float ly = py - fy, lx = pxf - fx;
            int y0 = (int)fy, x0 = (int)fx;
            int y1 = y0 + 1,  x1 = x0 + 1;
            bool vy0 = (y0 >= 0) && (y0 < H);
            bool vy1 = (y1 >= 0) && (y1 < H);
            bool vx0 = (x0 >= 0) && (x0 < W);
            bool vx1 = (x1 >= 0) && (x1 < W);
            float w0 = (vy0 && vx0) ? (1.f - ly) * (1.f - lx) * mk : 0.f;
            float w1 = (vy0 && vx1) ? (1.f - ly) * lx * mk : 0.f;
            float w2 = (vy1 && vx0) ? ly * (1.f - lx) * mk : 0.f;
            float w3 = (vy1 && vx1) ? ly * lx * mk : 0.f;
            int lc = min(max(x0, 0), W - 2);
            bool sel = (x0 == lc);
            int r0 = min(max(y0, 0), H - 1);
            int r1 = min(max(y1, 0), H - 1);
            moff[j][0] = (r0 * W + lc) * 4;
            moff[j][1] = (r1 * W + lc) * 4;
            wA0[j] = sel ? w0 : w1;  wB0[j] = sel ? w1 : w0;
            wA1[j] = sel ? w2 : w3;  wB1[j] = sel ? w3 : w2;
            int u0 = r0 - (ho - 2);
            int u1 = r1 - (ho - 2);
            int vvv = lc - (wo0 - 4);
            bool fastp = ((unsigned)u0 < 6u) && ((unsigned)u1 < 6u)
                       && ((unsigned)vvv < 71u);
            lidx1[j] = u1 * 72 + vvv;
            lidx0[j] = fastp ? (u0 * 72 + vvv) : -1;
        }
    }

    if (tid < 128) {                      // zero K-pad [144,160)
        short8 z = {0,0,0,0,0,0,0,0};
        *(short8*)&S[(tid >> 1) * LDK + 144 + (tid & 1) * 8] = z;
    }

    f32x4 acc[4][2];
    #pragma unroll
    for (int i = 0; i < 4; ++i)
        #pragma unroll
        for (int j = 0; j < 2; ++j)
            acc[i][j] = (f32x4){0.f, 0.f, 0.f, 0.f};

    // ---- sample half (channel base h*8, S parity par) from XW ----
    auto sample_h = [&](int h, int par) {
        #pragma unroll
        for (int j = 0; j < 3; ++j) {
            int s = tid + j * 256;
            if (s < 576) {
                int k = s >> 6, p = s & 63;
                float va[8];
                float wa0 = wA0[j], wb0 = wB0[j], wa1 = wA1[j], wb1 = wB1[j];
                if (lidx0[j] >= 0) {
                    int l0 = lidx0[j], l1 = lidx1[j];
                    #pragma unroll
                    for (int ci = 0; ci < 8; ++ci) {
                        const float* bp = &XW[ci * 432];
                        float a0 = bp[l0], a1 = bp[l0 + 1];
                        float b0 = bp[l1], b1 = bp[l1 + 1];
                        va[ci] = wa0 * a0 + wb0 * a1 + wa1 * b0 + wb1 * b1;
                    }
                } else {
                    #pragma unroll
                    for (int ci = 0; ci < 8; ++ci) {
                        const char* pc = (const char*)(xb + (size_t)(h * 8 + ci) * HW);
                        f32x2 A  = *(const f32x2a*)(pc + moff[j][0]);
                        f32x2 Bv = *(const f32x2a*)(pc + moff[j][1]);
                        va[ci] = wa0 * A.x + wb0 * A.y + wa1 * Bv.x + wb1 * Bv.y;
                    }
                }
                short8 sv;
                #pragma unroll
                for (int ci = 0; ci < 8; ++ci) sv[ci] = (short)f2bf(va[ci]);
                *(short8*)&S[p * LDK + k * 16 + par * 8] = sv;
            }
        }
    };

    auto mfma_step = [&](int c) {
        #pragma unroll
        for (int ks = 0; ks < 5; ++ks) {
            short8 a[4];
            #pragma unroll
            for (int of = 0; of < 4; ++of) {
                int o = oh + of * 16 + row16;
                a[of] = *(const short8*)(wbf + o * WBF_COLS + c * 160 + ks * 32 + kq * 8);
            }
            #pragma unroll
            for (int pf = 0; pf < 2; ++pf) {
                int p = ph + pf * 16 + row16;
                short8 bfr = *(const short8*)&S[p * LDK + ks * 32 + kq * 8];
                #pragma unroll
                for (int of = 0; of < 4; ++of)
                    acc[of][pf] = __builtin_amdgcn_mfma_f32_16x16x32_bf16(
                        a[of], bfr, acc[of][pf], 0, 0, 0);
            }
        }
    };

    // ---- pipelined, staggered main loop ----
    #pragma unroll 1
    for (int i = 0; i < 4; ++i) {
        int c = (i + r0rot) & 3;
        regwrite();                         // XW <- half 2c (readers synced)
        regload(2 * c + 1);                 // next half in flight
        __syncthreads();
        sample_h(2 * c, 0);
        __syncthreads();                    // XW reads done
        regwrite();                         // XW <- half 2c+1
        if (i < 3) regload(2 * (((i + 1) + r0rot) & 3));
        __syncthreads();
        sample_h(2 * c + 1, 1);
        __syncthreads();                    // S complete for chunk c
        mfma_step(c);
    }

    // ---- store: C/D layout col(px)=lane&15, row(o)=(lane>>4)*4+r ----
    #pragma unroll
    for (int of = 0; of < 4; ++of) {
        #pragma unroll
        for (int r = 0; r < 4; ++r) {
            int o = oh + of * 16 + kq * 4 + r;
            float* orow = out + ((b * COUT + o) * H + ho) * W;
            #pragma unroll
            for (int pf = 0; pf < 2; ++pf) {
                int wo = wo0 + ph + pf * 16 + row16;
                orow[wo] = acc[of][pf][r];
            }
        }
    }
}

// ---------------------------------------------------------------------------
extern "C" void kernel_launch(void* const* d_in, const int* in_sizes, int n_in,
                              void* d_out, int out_size, void* d_ws, size_t ws_size,
                              hipStream_t stream)
{
    const float* x      = (const float*)d_in[0];
    const float* w_off  = (const float*)d_in[1];
    const float* b_off  = (const float*)d_in[2];
    const float* w_mask = (const float*)d_in[3];
    const float* b_mask = (const float*)d_in[4];
    const float* weight = (const float*)d_in[5];
    float* out   = (float*)d_out;

    float* offs  = (float*)d_ws;
    float* maskb = offs + OFFS_SZ;
    float* bcat  = maskb + MASK_SZ;
    short* wbf   = (short*)(bcat + 32);
    float* wtap3 = bcat + 32 + WBF_SHORTS / 2;

    prep_kernel<<<dim3((WTAP3_SZ + 255) / 256), 256, 0, stream>>>(
        w_off, b_off, w_mask, b_mask, wtap3, bcat);
    prep_wbf<<<dim3((WBF_SHORTS + 255) / 256), 256, 0, stream>>>(weight, wbf);
    offmask2_kernel<<<dim3(1024), 256, 0, stream>>>(x, wtap3, bcat, offs, maskb);
    deform5_kernel<<<dim3(1024), 256, 0, stream>>>(x, offs, maskb, wbf, out);
}

// Round 7
// 312.557 us; speedup vs baseline: 4.0329x; 4.0329x over previous
//
#include <hip/hip_runtime.h>
#include <math.h>

#define B 4
#define CIN 64
#define H 128
#define W 128
#define COUT 128
#define KK 9
#define HW (H*W)

#define OFFS_SZ (B*18*HW)
#define MASK_SZ (B*9*HW)
#define WTAP3_SZ (CIN*9*28)          // [c][tap][f(28, 27 real)]
#define WBF_COLS 640                 // 4 chunks x 160 (144 real + 16 zero)
#define WBF_SHORTS (COUT*WBF_COLS)
#define LDK 168                      // LDS k-stride (shorts); 336B row stride

typedef __attribute__((ext_vector_type(8))) short short8;
typedef __attribute__((ext_vector_type(4))) float f32x4;
typedef __attribute__((ext_vector_type(2))) float f32x2;
typedef f32x2 __attribute__((aligned(4))) f32x2a;   // align-4 float2 load

__device__ __forceinline__ unsigned short f2bf(float f) {
    unsigned int u = __float_as_uint(f);
    u += 0x7fffu + ((u >> 16) & 1u);
    return (unsigned short)(u >> 16);
}

// ---------------------------------------------------------------------------
// prep: wtap3[(c*9+tap)*28+f] (f-contiguous), bcat biases.
// ---------------------------------------------------------------------------
__global__ void prep_kernel(const float* __restrict__ w_off, const float* __restrict__ b_off,
                            const float* __restrict__ w_mask, const float* __restrict__ b_mask,
                            float* __restrict__ wtap3, float* __restrict__ bcat)
{
    int idx = blockIdx.x * 256 + threadIdx.x;
    if (idx < WTAP3_SZ) {
        int c   = idx / 252;
        int rem = idx % 252;
        int tap = rem / 28;
        int f   = rem % 28;
        float v = 0.f;
        if (f < 18)      v = w_off[(f * CIN + c) * 9 + tap];
        else if (f < 27) v = w_mask[((f - 18) * CIN + c) * 9 + tap];
        wtap3[idx] = v;
    }
    if (blockIdx.x == 0 && threadIdx.x < 32) {
        int f = threadIdx.x;
        float bv = 0.f;
        if (f < 18) bv = b_off[f];
        else if (f < 27) bv = b_mask[f - 18];
        bcat[f] = bv;
    }
}

// ---------------------------------------------------------------------------
// prep_wbf: einsum weights -> bf16, layout [o][cb*160 + tap*16 + ci];
// pad cols [144,160) per chunk are ZERO.
// ---------------------------------------------------------------------------
__global__ void prep_wbf(const float* __restrict__ wgt, short* __restrict__ wbf)
{
    int idx = blockIdx.x * 256 + threadIdx.x;
    if (idx >= WBF_SHORTS) return;
    int o  = idx / WBF_COLS;
    int kp = idx % WBF_COLS;
    int cb = kp / 160, r = kp % 160;
    float v = 0.f;
    if (r < 144) {
        int tap = r >> 4;
        int c   = cb * 16 + (r & 15);
        v = wgt[(o * CIN + c) * KK + tap];
    }
    wbf[idx] = (short)f2bf(v);
}

// ---------------------------------------------------------------------------
// XCD band swizzle (kept): T = (bid%8)*(n/8)+bid/8.
// ---------------------------------------------------------------------------

// ---------------------------------------------------------------------------
// offmask3: lane = pixel, wave = 16-channel slice. SPILL-PROOF version of
// offmask2: filters processed in 3 passes of 9 (acc[9] + xv[9]x2 ~ 45 VGPRs,
// fits even the compiler's 64-VGPR choice that spilled acc[27] in R6).
// x re-read 3x (coalesced, L2-band resident) -- cheap; FMA count unchanged.
// ---------------------------------------------------------------------------
__global__ __launch_bounds__(256, 4) void offmask3_kernel(
    const float* __restrict__ x, const float* __restrict__ wtap3,
    const float* __restrict__ bcat, float* __restrict__ offs,
    float* __restrict__ mask)
{
    const int bid = blockIdx.x;
    const int T = (bid & 7) * 128 + (bid >> 3);
    const int wo0 = (T & 1) * 64;
    const int ho  = (T >> 1) & 127;
    const int b   = T >> 8;
    const int tid = threadIdx.x;
    const int w   = tid >> 6;            // wave -> 16-channel slice
    const int px  = tid & 63;            // lane -> pixel
    const int wo  = wo0 + px;

    __shared__ float co4[4 * 9 * 64];    // 9,216 B partial sums (per pass)

    const float* xb = x + (size_t)b * CIN * HW;

    #pragma unroll 1
    for (int g = 0; g < 3; ++g) {
        float acc[9];
        #pragma unroll
        for (int f = 0; f < 9; ++f) acc[f] = 0.f;

        float xvA[9], xvB[9];

        auto loadx = [&](int c, float* o9) {
            const float* xc = xb + (size_t)c * HW;
            #pragma unroll
            for (int ky = 0; ky < 3; ++ky) {
                int y = ho - 1 + ky;
                bool vy = ((unsigned)y < (unsigned)H);
                #pragma unroll
                for (int kx = 0; kx < 3; ++kx) {
                    int gg = wo - 1 + kx;
                    bool ok = vy && ((unsigned)gg < (unsigned)W);
                    o9[ky * 3 + kx] = ok ? xc[y * W + gg] : 0.f;
                }
            }
        };
        auto fma81 = [&](int c, const float* xv) {
            const float* wp = wtap3 + c * 252 + g * 9;   // wave-uniform
            #pragma unroll
            for (int tap = 0; tap < 9; ++tap) {
                float xvt = xv[tap];
                #pragma unroll
                for (int f = 0; f < 9; ++f)
                    acc[f] += wp[tap * 28 + f] * xvt;
            }
        };

        loadx(w * 16, xvA);
        #pragma unroll 1
        for (int ci = 0; ci < 16; ci += 2) {
            loadx(w * 16 + ci + 1, xvB);
            fma81(w * 16 + ci, xvA);
            if (ci + 2 < 16) loadx(w * 16 + ci + 2, xvA);
            fma81(w * 16 + ci + 1, xvB);
        }

        // cross-wave reduction + bias/sigmoid + store for this filter group
        if (g) __syncthreads();          // prior pass's reduction reads done
        #pragma unroll
        for (int f = 0; f < 9; ++f)
            co4[(w * 9 + f) * 64 + px] = acc[f];
        __syncthreads();
        #pragma unroll
        for (int i = 0; i < 3; ++i) {
            int idx = tid + i * 256;
            if (idx < 576) {
                float s = co4[idx] + co4[idx + 576] + co4[idx + 1152]
                        + co4[idx + 1728];
                int f = idx >> 6, p = idx & 63;
                int fg = g * 9 + f;
                s += bcat[fg];
                if (fg < 18) {
                    offs[((b * 18 + fg) * H + ho) * W + wo0 + p] = s;
                } else {
                    mask[((b * 9 + (fg - 18)) * H + ho) * W + wo0 + p] =
                        1.f / (1.f + expf(-s));
                }
            }
        }
    }
}

// ---------------------------------------------------------------------------
// deform5 (FROZEN from R6 -- validated ~35 us): LDS-window sampling with T14
// async staging + per-block chunk-order stagger.
// ---------------------------------------------------------------------------
__global__ __launch_bounds__(256, 4) void deform5_kernel(
    const float* __restrict__ x, const float* __restrict__ offs,
    const float* __restrict__ maskp, const short* __restrict__ wbf,
    float* __restrict__ out)
{
    const int bid = blockIdx.x;
    const int T = (bid & 7) * 128 + (bid >> 3);
    const int wo0 = (T & 1) * 64;
    const int ho  = (T >> 1) & 127;
    const int b   = T >> 8;
    const int tid  = threadIdx.x;
    const int lane = tid & 63;
    const int wv   = tid >> 6;
    const int oh   = (wv & 1) * 64;
    const int ph   = (wv >> 1) * 32;
    const int row16 = lane & 15, kq = lane >> 4;

    __shared__ __align__(16) float XW[8 * 6 * 72];    // 13,824 B
    __shared__ __align__(16) short S[64 * LDK];       // 21,504 B

    const float* xb = x + (size_t)b * CIN * HW;

    // ---- precompute per-thread staging slots (h-independent parts) ----
    int  st_lds[4]; int st_goff[4]; bool st_v[4], st_w[4];
    #pragma unroll
    for (int t = 0; t < 4; ++t) {
        int idx = tid + t * 256;
        st_w[t] = idx < 864;
        int ci = idx / 108, rem = idx % 108, row = rem / 18, q = rem % 18;
        int ys = min(max(ho - 2 + row, 0), H - 1);
        int g0 = wo0 - 4 + q * 4;
        st_lds[t]  = (ci * 6 + row) * 72 + q * 4;
        st_goff[t] = ci * HW + ys * W + g0;
        st_v[t] = st_w[t] && (g0 >= 0) && (g0 <= W - 4);
    }
    f32x4 rg[4];
    auto regload = [&](int h) {
        const float* base = xb + (size_t)h * 8 * HW;
        #pragma unroll
        for (int t = 0; t < 4; ++t) {
            f32x4 v = {0.f, 0.f, 0.f, 0.f};
            if (st_v[t]) v = *(const f32x4*)(base + st_goff[t]);
            rg[t] = v;
        }
    };
    auto regwrite = [&]() {
        #pragma unroll
        for (int t = 0; t < 4; ++t)
            if (st_w[t]) *(f32x4*)&XW[st_lds[t]] = rg[t];
    };

    const int r0rot = (int)((unsigned)(bid * 2654435761u) >> 30);  // 0..3

    regload(2 * r0rot);    // first window's loads in flight under metadata

    // ---- metadata: slot s = tid + j*256 -> (tap k = s>>6, px p = s&63) ----
    int   moff[3][2];
    int   lidx0[3], lidx1[3];
    float wA0[3], wB0[3], wA1[3], wB1[3];
    #pragma unroll
    for (int j = 0; j < 3; ++j) {
        moff[j][0] = 0; moff[j][1] = 0;
        lidx0[j] = -1; lidx1[j] = 0;
        wA0[j] = 0.f; wB0[j] = 0.f; wA1[j] = 0.f; wB1[j] = 0.f;
        int s = tid + j * 256;
        if (s < 576) {
            int k = s >> 6, p = s & 63;
            int wo = wo0 + p;
            int ky = k / 3, kx = k % 3;
            int obase = ((b * 18 + 2 * k) * H + ho) * W + wo;
            float dy = offs[obase];
            float dx = offs[obase + HW];
            float mk = maskp[((b * 9 + k) * H + ho) * W + wo];
            float py  = (float)(ho - 1 + ky) + dy;
            float pxf = (float)(wo - 1 + kx) + dx;
            float fy = floorf(py), fx = floorf(pxf);
            float ly = py - fy, lx = pxf - fx;
            int y0 = (int)fy, x0 = (int)fx;
            int y1 = y0 + 1,  x1 = x0 + 1;
            bool vy0 = (y0 >= 0) && (y0 < H);
            bool vy1 = (y1 >= 0) && (y1 < H);
            bool vx0 = (x0 >= 0) && (x0 < W);
            bool vx1 = (x1 >= 0) && (x1 < W);
            float w0 = (vy0 && vx0) ? (1.f - ly) * (1.f - lx) * mk : 0.f;
            float w1 = (vy0 && vx1) ? (1.f - ly) * lx * mk : 0.f;
            float w2 = (vy1 && vx0) ? ly * (1.f - lx) * mk : 0.f;
            float w3 = (vy1 && vx1) ? ly * lx * mk : 0.f;
            int lc = min(max(x0, 0), W - 2);
            bool sel = (x0 == lc);
            int r0 = min(max(y0, 0), H - 1);
            int r1 = min(max(y1, 0), H - 1);
            moff[j][0] = (r0 * W + lc) * 4;
            moff[j][1] = (r1 * W + lc) * 4;
            wA0[j] = sel ? w0 : w1;  wB0[j] = sel ? w1 : w0;
            wA1[j] = sel ? w2 : w3;  wB1[j] = sel ? w3 : w2;
            int u0 = r0 - (ho - 2);
            int u1 = r1 - (ho - 2);
            int vvv = lc - (wo0 - 4);
            bool fastp = ((unsigned)u0 < 6u) && ((unsigned)u1 < 6u)
                       && ((unsigned)vvv < 71u);
            lidx1[j] = u1 * 72 + vvv;
            lidx0[j] = fastp ? (u0 * 72 + vvv) : -1;
        }
    }

    if (tid < 128) {                      // zero K-pad [144,160)
        short8 z = {0,0,0,0,0,0,0,0};
        *(short8*)&S[(tid >> 1) * LDK + 144 + (tid & 1) * 8] = z;
    }

    f32x4 acc[4][2];
    #pragma unroll
    for (int i = 0; i < 4; ++i)
        #pragma unroll
        for (int j = 0; j < 2; ++j)
            acc[i][j] = (f32x4){0.f, 0.f, 0.f, 0.f};

    // ---- sample half (channel base h*8, S parity par) from XW ----
    auto sample_h = [&](int h, int par) {
        #pragma unroll
        for (int j = 0; j < 3; ++j) {
            int s = tid + j * 256;
            if (s < 576) {
                int k = s >> 6, p = s & 63;
                float va[8];
                float wa0 = wA0[j], wb0 = wB0[j], wa1 = wA1[j], wb1 = wB1[j];
                if (lidx0[j] >= 0) {
                    int l0 = lidx0[j], l1 = lidx1[j];
                    #pragma unroll
                    for (int ci = 0; ci < 8; ++ci) {
                        const float* bp = &XW[ci * 432];
                        float a0 = bp[l0], a1 = bp[l0 + 1];
                        float b0 = bp[l1], b1 = bp[l1 + 1];
                        va[ci] = wa0 * a0 + wb0 * a1 + wa1 * b0 + wb1 * b1;
                    }
                } else {
                    #pragma unroll
                    for (int ci = 0; ci < 8; ++ci) {
                        const char* pc = (const char*)(xb + (size_t)(h * 8 + ci) * HW);
                        f32x2 A  = *(const f32x2a*)(pc + moff[j][0]);
                        f32x2 Bv = *(const f32x2a*)(pc + moff[j][1]);
                        va[ci] = wa0 * A.x + wb0 * A.y + wa1 * Bv.x + wb1 * Bv.y;
                    }
                }
                short8 sv;
                #pragma unroll
                for (int ci = 0; ci < 8; ++ci) sv[ci] = (short)f2bf(va[ci]);
                *(short8*)&S[p * LDK + k * 16 + par * 8] = sv;
            }
        }
    };

    auto mfma_step = [&](int c) {
        #pragma unroll
        for (int ks = 0; ks < 5; ++ks) {
            short8 a[4];
            #pragma unroll
            for (int of = 0; of < 4; ++of) {
                int o = oh + of * 16 + row16;
                a[of] = *(const short8*)(wbf + o * WBF_COLS + c * 160 + ks * 32 + kq * 8);
            }
            #pragma unroll
            for (int pf = 0; pf < 2; ++pf) {
                int p = ph + pf * 16 + row16;
                short8 bfr = *(const short8*)&S[p * LDK + ks * 32 + kq * 8];
                #pragma unroll
                for (int of = 0; of < 4; ++of)
                    acc[of][pf] = __builtin_amdgcn_mfma_f32_16x16x32_bf16(
                        a[of], bfr, acc[of][pf], 0, 0, 0);
            }
        }
    };

    // ---- pipelined, staggered main loop ----
    #pragma unroll 1
    for (int i = 0; i < 4; ++i) {
        int c = (i + r0rot) & 3;
        regwrite();                         // XW <- half 2c (readers synced)
        regload(2 * c + 1);                 // next half in flight
        __syncthreads();
        sample_h(2 * c, 0);
        __syncthreads();                    // XW reads done
        regwrite();                         // XW <- half 2c+1
        if (i < 3) regload(2 * (((i + 1) + r0rot) & 3));
        __syncthreads();
        sample_h(2 * c + 1, 1);
        __syncthreads();                    // S complete for chunk c
        mfma_step(c);
    }

    // ---- store: C/D layout col(px)=lane&15, row(o)=(lane>>4)*4+r ----
    #pragma unroll
    for (int of = 0; of < 4; ++of) {
        #pragma unroll
        for (int r = 0; r < 4; ++r) {
            int o = oh + of * 16 + kq * 4 + r;
            float* orow = out + ((b * COUT + o) * H + ho) * W;
            #pragma unroll
            for (int pf = 0; pf < 2; ++pf) {
                int wo = wo0 + ph + pf * 16 + row16;
                orow[wo] = acc[of][pf][r];
            }
        }
    }
}

// ---------------------------------------------------------------------------
extern "C" void kernel_launch(void* const* d_in, const int* in_sizes, int n_in,
                              void* d_out, int out_size, void* d_ws, size_t ws_size,
                              hipStream_t stream)
{
    const float* x      = (const float*)d_in[0];
    const float* w_off  = (const float*)d_in[1];
    const float* b_off  = (const float*)d_in[2];
    const float* w_mask = (const float*)d_in[3];
    const float* b_mask = (const float*)d_in[4];
    const float* weight = (const float*)d_in[5];
    float* out   = (float*)d_out;

    float* offs  = (float*)d_ws;
    float* maskb = offs + OFFS_SZ;
    float* bcat  = maskb + MASK_SZ;
    short* wbf   = (short*)(bcat + 32);
    float* wtap3 = bcat + 32 + WBF_SHORTS / 2;

    prep_kernel<<<dim3((WTAP3_SZ + 255) / 256), 256, 0, stream>>>(
        w_off, b_off, w_mask, b_mask, wtap3, bcat);
    prep_wbf<<<dim3((WBF_SHORTS + 255) / 256), 256, 0, stream>>>(weight, wbf);
    offmask3_kernel<<<dim3(1024), 256, 0, stream>>>(x, wtap3, bcat, offs, maskb);
    deform5_kernel<<<dim3(1024), 256, 0, stream>>>(x, offs, maskb, wbf, out);
}

// Round 8
// 168.369 us; speedup vs baseline: 7.4866x; 1.8564x over previous
//
#include <hip/hip_runtime.h>
#include <math.h>

#define B 4
#define CIN 64
#define H 128
#define W 128
#define COUT 128
#define KK 9
#define HW (H*W)

#define OFFS_SZ (B*18*HW)
#define MASK_SZ (B*9*HW)
#define WTAP3_SZ (CIN*9*28)          // [c][tap][f(28, 27 real)]
#define WBF_COLS 640                 // 4 chunks x 160 (144 real + 16 zero)
#define WBF_SHORTS (COUT*WBF_COLS)
#define LDK 168                      // LDS k-stride (shorts); 336B row stride

typedef __attribute__((ext_vector_type(8))) short short8;
typedef __attribute__((ext_vector_type(4))) float f32x4;
typedef __attribute__((ext_vector_type(2))) float f32x2;
typedef f32x2 __attribute__((aligned(4))) f32x2a;   // align-4 float2 load

__device__ __forceinline__ unsigned short f2bf(float f) {
    unsigned int u = __float_as_uint(f);
    u += 0x7fffu + ((u >> 16) & 1u);
    return (unsigned short)(u >> 16);
}

// ---------------------------------------------------------------------------
// prep: wtap3[(c*9+tap)*28+f] (f-contiguous), bcat biases.
// ---------------------------------------------------------------------------
__global__ void prep_kernel(const float* __restrict__ w_off, const float* __restrict__ b_off,
                            const float* __restrict__ w_mask, const float* __restrict__ b_mask,
                            float* __restrict__ wtap3, float* __restrict__ bcat)
{
    int idx = blockIdx.x * 256 + threadIdx.x;
    if (idx < WTAP3_SZ) {
        int c   = idx / 252;
        int rem = idx % 252;
        int tap = rem / 28;
        int f   = rem % 28;
        float v = 0.f;
        if (f < 18)      v = w_off[(f * CIN + c) * 9 + tap];
        else if (f < 27) v = w_mask[((f - 18) * CIN + c) * 9 + tap];
        wtap3[idx] = v;
    }
    if (blockIdx.x == 0 && threadIdx.x < 32) {
        int f = threadIdx.x;
        float bv = 0.f;
        if (f < 18) bv = b_off[f];
        else if (f < 27) bv = b_mask[f - 18];
        bcat[f] = bv;
    }
}

// ---------------------------------------------------------------------------
// prep_wbf: einsum weights -> bf16, layout [o][cb*160 + tap*16 + ci];
// pad cols [144,160) per chunk are ZERO.
// ---------------------------------------------------------------------------
__global__ void prep_wbf(const float* __restrict__ wgt, short* __restrict__ wbf)
{
    int idx = blockIdx.x * 256 + threadIdx.x;
    if (idx >= WBF_SHORTS) return;
    int o  = idx / WBF_COLS;
    int kp = idx % WBF_COLS;
    int cb = kp / 160, r = kp % 160;
    float v = 0.f;
    if (r < 144) {
        int tap = r >> 4;
        int c   = cb * 16 + (r & 15);
        v = wgt[(o * CIN + c) * KK + tap];
    }
    wbf[idx] = (short)f2bf(v);
}

// ---------------------------------------------------------------------------
// XCD band swizzle (kept): T = (bid%8)*(n/8)+bid/8.
// ---------------------------------------------------------------------------

// ---------------------------------------------------------------------------
// offmask4: lane = pixel, wave = 16-channel slice, acc[27] in registers.
// SPILL FIX: amdgpu_waves_per_eu(4,4) pins occupancy at 4 waves/EU ->
// 128-VGPR budget and NO incentive for the allocator to shrink-and-spill
// (R6/R7 failure mode: heuristic chose 64 VGPR + scratch for 8 waves/EU).
// Weights fetched via readfirstlane'd pointer -> SMEM/scalar-cache loads.
// ---------------------------------------------------------------------------
__global__ __launch_bounds__(256)
__attribute__((amdgpu_waves_per_eu(4, 4)))
void offmask4_kernel(
    const float* __restrict__ x, const float* __restrict__ wtap3,
    const float* __restrict__ bcat, float* __restrict__ offs,
    float* __restrict__ mask)
{
    const int bid = blockIdx.x;
    const int T = (bid & 7) * 128 + (bid >> 3);
    const int wo0 = (T & 1) * 64;
    const int ho  = (T >> 1) & 127;
    const int b   = T >> 8;
    const int tid = threadIdx.x;
    const int w   = tid >> 6;            // wave -> 16-channel slice
    const int px  = tid & 63;            // lane -> pixel
    const int wo  = wo0 + px;

    __shared__ float co4[4 * 27 * 64];   // 27,648 B partial sums

    float acc[27];
    #pragma unroll
    for (int f = 0; f < 27; ++f) acc[f] = 0.f;

    const float* xb = x + (size_t)b * CIN * HW;

    auto loadx = [&](int c, float* o9) {
        const float* xc = xb + (size_t)c * HW;
        #pragma unroll
        for (int ky = 0; ky < 3; ++ky) {
            int y = ho - 1 + ky;
            bool vy = ((unsigned)y < (unsigned)H);
            #pragma unroll
            for (int kx = 0; kx < 3; ++kx) {
                int g = wo - 1 + kx;
                bool ok = vy && ((unsigned)g < (unsigned)W);
                o9[ky * 3 + kx] = ok ? xc[y * W + g] : 0.f;
            }
        }
    };
    auto fma243 = [&](int c, const float* xv) {
        int cs = __builtin_amdgcn_readfirstlane(c);     // wave-uniform -> SGPR
        const float* wp = wtap3 + cs * 252;             // SMEM loads
        #pragma unroll
        for (int tap = 0; tap < 9; ++tap) {
            float xvt = xv[tap];
            #pragma unroll
            for (int f = 0; f < 27; ++f)
                acc[f] += wp[tap * 28 + f] * xvt;
        }
    };

    float xvA[9], xvB[9];
    loadx(w * 16, xvA);
    #pragma unroll 1
    for (int ci = 0; ci < 16; ci += 2) {
        loadx(w * 16 + ci + 1, xvB);
        fma243(w * 16 + ci, xvA);
        if (ci + 2 < 16) loadx(w * 16 + ci + 2, xvA);
        fma243(w * 16 + ci + 1, xvB);
    }

    // cross-wave reduction + bias/sigmoid + store
    #pragma unroll
    for (int f = 0; f < 27; ++f)
        co4[(w * 27 + f) * 64 + px] = acc[f];
    __syncthreads();
    #pragma unroll
    for (int i = 0; i < 7; ++i) {
        int idx = tid + i * 256;
        if (idx < 27 * 64) {
            float s = co4[idx] + co4[idx + 1728] + co4[idx + 2 * 1728]
                    + co4[idx + 3 * 1728];
            int f = idx >> 6, p = idx & 63;
            s += bcat[f];
            if (f < 18) {
                offs[((b * 18 + f) * H + ho) * W + wo0 + p] = s;
            } else {
                mask[((b * 9 + (f - 18)) * H + ho) * W + wo0 + p] =
                    1.f / (1.f + expf(-s));
            }
        }
    }
}

// ---------------------------------------------------------------------------
// deform5 (FROZEN -- validated ~35 us): LDS-window sampling with T14 async
// staging + per-block chunk-order stagger.
// ---------------------------------------------------------------------------
__global__ __launch_bounds__(256, 4) void deform5_kernel(
    const float* __restrict__ x, const float* __restrict__ offs,
    const float* __restrict__ maskp, const short* __restrict__ wbf,
    float* __restrict__ out)
{
    const int bid = blockIdx.x;
    const int T = (bid & 7) * 128 + (bid >> 3);
    const int wo0 = (T & 1) * 64;
    const int ho  = (T >> 1) & 127;
    const int b   = T >> 8;
    const int tid  = threadIdx.x;
    const int lane = tid & 63;
    const int wv   = tid >> 6;
    const int oh   = (wv & 1) * 64;
    const int ph   = (wv >> 1) * 32;
    const int row16 = lane & 15, kq = lane >> 4;

    __shared__ __align__(16) float XW[8 * 6 * 72];    // 13,824 B
    __shared__ __align__(16) short S[64 * LDK];       // 21,504 B

    const float* xb = x + (size_t)b * CIN * HW;

    // ---- precompute per-thread staging slots (h-independent parts) ----
    int  st_lds[4]; int st_goff[4]; bool st_v[4], st_w[4];
    #pragma unroll
    for (int t = 0; t < 4; ++t) {
        int idx = tid + t * 256;
        st_w[t] = idx < 864;
        int ci = idx / 108, rem = idx % 108, row = rem / 18, q = rem % 18;
        int ys = min(max(ho - 2 + row, 0), H - 1);
        int g0 = wo0 - 4 + q * 4;
        st_lds[t]  = (ci * 6 + row) * 72 + q * 4;
        st_goff[t] = ci * HW + ys * W + g0;
        st_v[t] = st_w[t] && (g0 >= 0) && (g0 <= W - 4);
    }
    f32x4 rg[4];
    auto regload = [&](int h) {
        const float* base = xb + (size_t)h * 8 * HW;
        #pragma unroll
        for (int t = 0; t < 4; ++t) {
            f32x4 v = {0.f, 0.f, 0.f, 0.f};
            if (st_v[t]) v = *(const f32x4*)(base + st_goff[t]);
            rg[t] = v;
        }
    };
    auto regwrite = [&]() {
        #pragma unroll
        for (int t = 0; t < 4; ++t)
            if (st_w[t]) *(f32x4*)&XW[st_lds[t]] = rg[t];
    };

    const int r0rot = (int)((unsigned)(bid * 2654435761u) >> 30);  // 0..3

    regload(2 * r0rot);    // first window's loads in flight under metadata

    // ---- metadata: slot s = tid + j*256 -> (tap k = s>>6, px p = s&63) ----
    int   moff[3][2];
    int   lidx0[3], lidx1[3];
    float wA0[3], wB0[3], wA1[3], wB1[3];
    #pragma unroll
    for (int j = 0; j < 3; ++j) {
        moff[j][0] = 0; moff[j][1] = 0;
        lidx0[j] = -1; lidx1[j] = 0;
        wA0[j] = 0.f; wB0[j] = 0.f; wA1[j] = 0.f; wB1[j] = 0.f;
        int s = tid + j * 256;
        if (s < 576) {
            int k = s >> 6, p = s & 63;
            int wo = wo0 + p;
            int ky = k / 3, kx = k % 3;
            int obase = ((b * 18 + 2 * k) * H + ho) * W + wo;
            float dy = offs[obase];
            float dx = offs[obase + HW];
            float mk = maskp[((b * 9 + k) * H + ho) * W + wo];
            float py  = (float)(ho - 1 + ky) + dy;
            float pxf = (float)(wo - 1 + kx) + dx;
            float fy = floorf(py), fx = floorf(pxf);
            float ly = py - fy, lx = pxf - fx;
            int y0 = (int)fy, x0 = (int)fx;
            int y1 = y0 + 1,  x1 = x0 + 1;
            bool vy0 = (y0 >= 0) && (y0 < H);
            bool vy1 = (y1 >= 0) && (y1 < H);
            bool vx0 = (x0 >= 0) && (x0 < W);
            bool vx1 = (x1 >= 0) && (x1 < W);
            float w0 = (vy0 && vx0) ? (1.f - ly) * (1.f - lx) * mk : 0.f;
            float w1 = (vy0 && vx1) ? (1.f - ly) * lx * mk : 0.f;
            float w2 = (vy1 && vx0) ? ly * (1.f - lx) * mk : 0.f;
            float w3 = (vy1 && vx1) ? ly * lx * mk : 0.f;
            int lc = min(max(x0, 0), W - 2);
            bool sel = (x0 == lc);
            int r0 = min(max(y0, 0), H - 1);
            int r1 = min(max(y1, 0), H - 1);
            moff[j][0] = (r0 * W + lc) * 4;
            moff[j][1] = (r1 * W + lc) * 4;
            wA0[j] = sel ? w0 : w1;  wB0[j] = sel ? w1 : w0;
            wA1[j] = sel ? w2 : w3;  wB1[j] = sel ? w3 : w2;
            int u0 = r0 - (ho - 2);
            int u1 = r1 - (ho - 2);
            int vvv = lc - (wo0 - 4);
            bool fastp = ((unsigned)u0 < 6u) && ((unsigned)u1 < 6u)
                       && ((unsigned)vvv < 71u);
            lidx1[j] = u1 * 72 + vvv;
            lidx0[j] = fastp ? (u0 * 72 + vvv) : -1;
        }
    }

    if (tid < 128) {                      // zero K-pad [144,160)
        short8 z = {0,0,0,0,0,0,0,0};
        *(short8*)&S[(tid >> 1) * LDK + 144 + (tid & 1) * 8] = z;
    }

    f32x4 acc[4][2];
    #pragma unroll
    for (int i = 0; i < 4; ++i)
        #pragma unroll
        for (int j = 0; j < 2; ++j)
            acc[i][j] = (f32x4){0.f, 0.f, 0.f, 0.f};

    // ---- sample half (channel base h*8, S parity par) from XW ----
    auto sample_h = [&](int h, int par) {
        #pragma unroll
        for (int j = 0; j < 3; ++j) {
            int s = tid + j * 256;
            if (s < 576) {
                int k = s >> 6, p = s & 63;
                float va[8];
                float wa0 = wA0[j], wb0 = wB0[j], wa1 = wA1[j], wb1 = wB1[j];
                if (lidx0[j] >= 0) {
                    int l0 = lidx0[j], l1 = lidx1[j];
                    #pragma unroll
                    for (int ci = 0; ci < 8; ++ci) {
                        const float* bp = &XW[ci * 432];
                        float a0 = bp[l0], a1 = bp[l0 + 1];
                        float b0 = bp[l1], b1 = bp[l1 + 1];
                        va[ci] = wa0 * a0 + wb0 * a1 + wa1 * b0 + wb1 * b1;
                    }
                } else {
                    #pragma unroll
                    for (int ci = 0; ci < 8; ++ci) {
                        const char* pc = (const char*)(xb + (size_t)(h * 8 + ci) * HW);
                        f32x2 A  = *(const f32x2a*)(pc + moff[j][0]);
                        f32x2 Bv = *(const f32x2a*)(pc + moff[j][1]);
                        va[ci] = wa0 * A.x + wb0 * A.y + wa1 * Bv.x + wb1 * Bv.y;
                    }
                }
                short8 sv;
                #pragma unroll
                for (int ci = 0; ci < 8; ++ci) sv[ci] = (short)f2bf(va[ci]);
                *(short8*)&S[p * LDK + k * 16 + par * 8] = sv;
            }
        }
    };

    auto mfma_step = [&](int c) {
        #pragma unroll
        for (int ks = 0; ks < 5; ++ks) {
            short8 a[4];
            #pragma unroll
            for (int of = 0; of < 4; ++of) {
                int o = oh + of * 16 + row16;
                a[of] = *(const short8*)(wbf + o * WBF_COLS + c * 160 + ks * 32 + kq * 8);
            }
            #pragma unroll
            for (int pf = 0; pf < 2; ++pf) {
                int p = ph + pf * 16 + row16;
                short8 bfr = *(const short8*)&S[p * LDK + ks * 32 + kq * 8];
                #pragma unroll
                for (int of = 0; of < 4; ++of)
                    acc[of][pf] = __builtin_amdgcn_mfma_f32_16x16x32_bf16(
                        a[of], bfr, acc[of][pf], 0, 0, 0);
            }
        }
    };

    // ---- pipelined, staggered main loop ----
    #pragma unroll 1
    for (int i = 0; i < 4; ++i) {
        int c = (i + r0rot) & 3;
        regwrite();                         // XW <- half 2c (readers synced)
        regload(2 * c + 1);                 // next half in flight
        __syncthreads();
        sample_h(2 * c, 0);
        __syncthreads();                    // XW reads done
        regwrite();                         // XW <- half 2c+1
        if (i < 3) regload(2 * (((i + 1) + r0rot) & 3));
        __syncthreads();
        sample_h(2 * c + 1, 1);
        __syncthreads();                    // S complete for chunk c
        mfma_step(c);
    }

    // ---- store: C/D layout col(px)=lane&15, row(o)=(lane>>4)*4+r ----
    #pragma unroll
    for (int of = 0; of < 4; ++of) {
        #pragma unroll
        for (int r = 0; r < 4; ++r) {
            int o = oh + of * 16 + kq * 4 + r;
            float* orow = out + ((b * COUT + o) * H + ho) * W;
            #pragma unroll
            for (int pf = 0; pf < 2; ++pf) {
                int wo = wo0 + ph + pf * 16 + row16;
                orow[wo] = acc[of][pf][r];
            }
        }
    }
}

// ---------------------------------------------------------------------------
extern "C" void kernel_launch(void* const* d_in, const int* in_sizes, int n_in,
                              void* d_out, int out_size, void* d_ws, size_t ws_size,
                              hipStream_t stream)
{
    const float* x      = (const float*)d_in[0];
    const float* w_off  = (const float*)d_in[1];
    const float* b_off  = (const float*)d_in[2];
    const float* w_mask = (const float*)d_in[3];
    const float* b_mask = (const float*)d_in[4];
    const float* weight = (const float*)d_in[5];
    float* out   = (float*)d_out;

    float* offs  = (float*)d_ws;
    float* maskb = offs + OFFS_SZ;
    float* bcat  = maskb + MASK_SZ;
    short* wbf   = (short*)(bcat + 32);
    float* wtap3 = bcat + 32 + WBF_SHORTS / 2;

    prep_kernel<<<dim3((WTAP3_SZ + 255) / 256), 256, 0, stream>>>(
        w_off, b_off, w_mask, b_mask, wtap3, bcat);
    prep_wbf<<<dim3((WBF_SHORTS + 255) / 256), 256, 0, stream>>>(weight, wbf);
    offmask4_kernel<<<dim3(1024), 256, 0, stream>>>(x, wtap3, bcat, offs, maskb);
    deform5_kernel<<<dim3(1024), 256, 0, stream>>>(x, offs, maskb, wbf, out);
}

// Round 9
// 138.956 us; speedup vs baseline: 9.0713x; 1.2117x over previous
//
#include <hip/hip_runtime.h>
#include <math.h>

#define B 4
#define CIN 64
#define H 128
#define W 128
#define COUT 128
#define KK 9
#define HW (H*W)

#define OFFS_SZ (B*18*HW)
#define MASK_SZ (B*9*HW)
#define WTAP2_SZ (CIN*32*12)         // [c][f][12] (t-contiguous)
#define WBF_COLS 640                 // 4 chunks x 160 (144 real + 16 zero)
#define WBF_SHORTS (COUT*WBF_COLS)
#define LDK 168                      // LDS k-stride (shorts); 336B row stride

typedef __attribute__((ext_vector_type(8))) short short8;
typedef __attribute__((ext_vector_type(4))) float f32x4;
typedef __attribute__((ext_vector_type(2))) float f32x2;
typedef f32x2 __attribute__((aligned(4))) f32x2a;   // align-4 float2 load

__device__ __forceinline__ unsigned short f2bf(float f) {
    unsigned int u = __float_as_uint(f);
    u += 0x7fffu + ((u >> 16) & 1u);
    return (unsigned short)(u >> 16);
}

// ---------------------------------------------------------------------------
// prep: wtap2[c][f][12] (t-contiguous for b128 LDS reads), bcat biases.
// ---------------------------------------------------------------------------
__global__ void prep_kernel(const float* __restrict__ w_off, const float* __restrict__ b_off,
                            const float* __restrict__ w_mask, const float* __restrict__ b_mask,
                            float* __restrict__ wtap2, float* __restrict__ bcat)
{
    int idx = blockIdx.x * 256 + threadIdx.x;
    if (idx < WTAP2_SZ) {
        int t = idx % 12;
        int f = (idx / 12) & 31;
        int c = idx / 384;
        float v = 0.f;
        if (t < 9) {
            if (f < 18)      v = w_off[(f * CIN + c) * 9 + t];
            else if (f < 27) v = w_mask[((f - 18) * CIN + c) * 9 + t];
        }
        wtap2[idx] = v;
    }
    if (blockIdx.x == 0 && threadIdx.x < 32) {
        int f = threadIdx.x;
        float bv = 0.f;
        if (f < 18) bv = b_off[f];
        else if (f < 27) bv = b_mask[f - 18];
        bcat[f] = bv;
    }
}

// ---------------------------------------------------------------------------
// prep_wbf: einsum weights -> bf16, layout [o][cb*160 + tap*16 + ci];
// pad cols [144,160) per chunk are ZERO.
// ---------------------------------------------------------------------------
__global__ void prep_wbf(const float* __restrict__ wgt, short* __restrict__ wbf)
{
    int idx = blockIdx.x * 256 + threadIdx.x;
    if (idx >= WBF_SHORTS) return;
    int o  = idx / WBF_COLS;
    int kp = idx % WBF_COLS;
    int cb = kp / 160, r = kp % 160;
    float v = 0.f;
    if (r < 144) {
        int tap = r >> 4;
        int c   = cb * 16 + (r & 15);
        v = wgt[(o * CIN + c) * KK + tap];
    }
    wbf[idx] = (short)f2bf(v);
}

// ---------------------------------------------------------------------------
// XCD band swizzle (kept): T = (bid%8)*(n/8)+bid/8. NO per-block chunk
// stagger anywhere (R8 post-mortem: stagger tripled deform FETCH_SIZE).
// ---------------------------------------------------------------------------

// ---------------------------------------------------------------------------
// offmask5: R5's validated 48us structure (LDS-staged x + weights, async
// reg-staged next-chunk loads, channel unroll 2) + waves_per_eu(4,4) pin
// so the allocator gets a 128-VGPR budget instead of shrinking to 64 and
// spilling (R6-R8 lesson; offmask4's 234->68 was this same fix).
// ---------------------------------------------------------------------------
#define CC 8
__global__ __launch_bounds__(256)
__attribute__((amdgpu_waves_per_eu(4, 4)))
void offmask5_kernel(
    const float* __restrict__ x, const float* __restrict__ wtap2,
    const float* __restrict__ bcat, float* __restrict__ offs,
    float* __restrict__ mask)
{
    const int bid = blockIdx.x;
    const int T = (bid & 7) * 128 + (bid >> 3);
    const int wo0 = (T & 1) * 64;
    const int ho  = (T >> 1) & 127;
    const int b   = T >> 8;
    const int tid = threadIdx.x;
    const int f   = tid & 31;
    const int pg  = tid >> 5;
    const int px0 = pg * 8;

    __shared__ float lx[CC * 3 * 72];     // 6,912 B (base x = wo0-1)
    __shared__ float lw2[CC * 32 * 12];   // 12,288 B

    float acc[8];
    #pragma unroll
    for (int i = 0; i < 8; ++i) acc[i] = 0.f;

    const float* xb = x + b * CIN * HW;

    float nx[7], nw[12];
    auto load_chunk = [&](int cb) {
        #pragma unroll
        for (int i = 0; i < 7; ++i) {
            int idx = tid + i * 256;
            float v = 0.f;
            if (idx < CC * 3 * 72) {
                int c  = idx / 216;
                int rem = idx % 216;
                int ry = rem / 72;
                int j  = rem % 72;
                int g  = wo0 - 1 + j;
                int y  = ho - 1 + ry;
                if (y >= 0 && y < H && g >= 0 && g < W)
                    v = xb[(cb + c) * HW + y * W + g];
            }
            nx[i] = v;
        }
        #pragma unroll
        for (int i = 0; i < 12; ++i)
            nw[i] = wtap2[cb * (32 * 12) + tid + i * 256];
    };
    auto store_chunk = [&]() {
        #pragma unroll
        for (int i = 0; i < 7; ++i) {
            int idx = tid + i * 256;
            if (idx < CC * 3 * 72) lx[idx] = nx[i];
        }
        #pragma unroll
        for (int i = 0; i < 12; ++i)
            lw2[tid + i * 256] = nw[i];
    };

    load_chunk(0);
    store_chunk();
    __syncthreads();

    for (int cb = 0; cb < CIN; cb += CC) {
        bool more = (cb + CC) < CIN;
        if (more) load_chunk(cb + CC);   // in-flight during compute below

        #pragma unroll 2
        for (int c = 0; c < CC; ++c) {
            const float* wrow = &lw2[(c * 32 + f) * 12];
            f32x4 wq0 = *(const f32x4*)wrow;
            f32x4 wq1 = *(const f32x4*)(wrow + 4);
            float wv[9] = {wq0.x, wq0.y, wq0.z, wq0.w,
                           wq1.x, wq1.y, wq1.z, wq1.w, wrow[8]};
            float xr[3][10];
            #pragma unroll
            for (int q = 0; q < 3; ++q) {
                const float* xrow = &lx[(c * 3 + q) * 72 + px0];
                f32x4 xa = *(const f32x4*)xrow;
                f32x4 xb4 = *(const f32x4*)(xrow + 4);
                f32x2 xc = *(const f32x2*)(xrow + 8);
                xr[q][0] = xa.x;  xr[q][1] = xa.y;  xr[q][2] = xa.z;  xr[q][3] = xa.w;
                xr[q][4] = xb4.x; xr[q][5] = xb4.y; xr[q][6] = xb4.z; xr[q][7] = xb4.w;
                xr[q][8] = xc.x;  xr[q][9] = xc.y;
            }
            #pragma unroll
            for (int ky = 0; ky < 3; ++ky) {
                #pragma unroll
                for (int kx = 0; kx < 3; ++kx) {
                    float w = wv[ky * 3 + kx];
                    #pragma unroll
                    for (int p = 0; p < 8; ++p)
                        acc[p] += xr[ky][p + kx] * w;
                }
            }
        }

        if (more) {
            __syncthreads();     // all reads of lx/lw2 done
            store_chunk();
            __syncthreads();
        }
    }

    const float bv = bcat[f];
    if (f < 18) {
        float* op = offs + ((b * 18 + f) * H + ho) * W + wo0 + px0;
        #pragma unroll
        for (int p = 0; p < 8; ++p) op[p] = acc[p] + bv;
    } else if (f < 27) {
        float* mp = mask + ((b * 9 + (f - 18)) * H + ho) * W + wo0 + px0;
        #pragma unroll
        for (int p = 0; p < 8; ++p) {
            float a = acc[p] + bv;
            mp[p] = 1.f / (1.f + expf(-a));
        }
    }
}

// ---------------------------------------------------------------------------
// deform6: deform4 structure (NO stagger -> restores cross-block L2 reuse,
// FETCH ~20MB) + async reg-staged window loads (regload issued a phase early,
// ds_write after the barrier) + waves_per_eu(4,4) spill pin.
// LDS 35,328 B -> 4 blocks/CU.
// ---------------------------------------------------------------------------
__global__ __launch_bounds__(256)
__attribute__((amdgpu_waves_per_eu(4, 4)))
void deform6_kernel(
    const float* __restrict__ x, const float* __restrict__ offs,
    const float* __restrict__ maskp, const short* __restrict__ wbf,
    float* __restrict__ out)
{
    const int bid = blockIdx.x;
    const int T = (bid & 7) * 128 + (bid >> 3);
    const int wo0 = (T & 1) * 64;
    const int ho  = (T >> 1) & 127;
    const int b   = T >> 8;
    const int tid  = threadIdx.x;
    const int lane = tid & 63;
    const int wv   = tid >> 6;
    const int oh   = (wv & 1) * 64;
    const int ph   = (wv >> 1) * 32;
    const int row16 = lane & 15, kq = lane >> 4;

    __shared__ __align__(16) float XW[8 * 6 * 72];    // 13,824 B
    __shared__ __align__(16) short S[64 * LDK];       // 21,504 B

    const float* xb = x + (size_t)b * CIN * HW;

    // ---- precompute per-thread staging slots (h-independent parts) ----
    int  st_lds[4]; int st_goff[4]; bool st_v[4], st_w[4];
    #pragma unroll
    for (int t = 0; t < 4; ++t) {
        int idx = tid + t * 256;
        st_w[t] = idx < 864;
        int ci = idx / 108, rem = idx % 108, row = rem / 18, q = rem % 18;
        int ys = min(max(ho - 2 + row, 0), H - 1);
        int g0 = wo0 - 4 + q * 4;
        st_lds[t]  = (ci * 6 + row) * 72 + q * 4;
        st_goff[t] = ci * HW + ys * W + g0;
        st_v[t] = st_w[t] && (g0 >= 0) && (g0 <= W - 4);
    }
    f32x4 rg[4];
    auto regload = [&](int h) {
        const float* base = xb + (size_t)h * 8 * HW;
        #pragma unroll
        for (int t = 0; t < 4; ++t) {
            f32x4 v = {0.f, 0.f, 0.f, 0.f};
            if (st_v[t]) v = *(const f32x4*)(base + st_goff[t]);
            rg[t] = v;
        }
    };
    auto regwrite = [&]() {
        #pragma unroll
        for (int t = 0; t < 4; ++t)
            if (st_w[t]) *(f32x4*)&XW[st_lds[t]] = rg[t];
    };

    regload(0);    // first window's loads in flight under metadata compute

    // ---- metadata: slot s = tid + j*256 -> (tap k = s>>6, px p = s&63) ----
    int   moff[3][2];
    int   lidx0[3], lidx1[3];
    float wA0[3], wB0[3], wA1[3], wB1[3];
    #pragma unroll
    for (int j = 0; j < 3; ++j) {
        moff[j][0] = 0; moff[j][1] = 0;
        lidx0[j] = -1; lidx1[j] = 0;
        wA0[j] = 0.f; wB0[j] = 0.f; wA1[j] = 0.f; wB1[j] = 0.f;
        int s = tid + j * 256;
        if (s < 576) {
            int k = s >> 6, p = s & 63;
            int wo = wo0 + p;
            int ky = k / 3, kx = k % 3;
            int obase = ((b * 18 + 2 * k) * H + ho) * W + wo;
            float dy = offs[obase];
            float dx = offs[obase + HW];
            float mk = maskp[((b * 9 + k) * H + ho) * W + wo];
            float py  = (float)(ho - 1 + ky) + dy;
            float pxf = (float)(wo - 1 + kx) + dx;
            float fy = floorf(py), fx = floorf(pxf);
            float ly = py - fy, lx = pxf - fx;
            int y0 = (int)fy, x0 = (int)fx;
            int y1 = y0 + 1,  x1 = x0 + 1;
            bool vy0 = (y0 >= 0) && (y0 < H);
            bool vy1 = (y1 >= 0) && (y1 < H);
            bool vx0 = (x0 >= 0) && (x0 < W);
            bool vx1 = (x1 >= 0) && (x1 < W);
            float w0 = (vy0 && vx0) ? (1.f - ly) * (1.f - lx) * mk : 0.f;
            float w1 = (vy0 && vx1) ? (1.f - ly) * lx * mk : 0.f;
            float w2 = (vy1 && vx0) ? ly * (1.f - lx) * mk : 0.f;
            float w3 = (vy1 && vx1) ? ly * lx * mk : 0.f;
            int lc = min(max(x0, 0), W - 2);
            bool sel = (x0 == lc);
            int r0 = min(max(y0, 0), H - 1);
            int r1 = min(max(y1, 0), H - 1);
            moff[j][0] = (r0 * W + lc) * 4;
            moff[j][1] = (r1 * W + lc) * 4;
            wA0[j] = sel ? w0 : w1;  wB0[j] = sel ? w1 : w0;
            wA1[j] = sel ? w2 : w3;  wB1[j] = sel ? w3 : w2;
            int u0 = r0 - (ho - 2);
            int u1 = r1 - (ho - 2);
            int vvv = lc - (wo0 - 4);
            bool fastp = ((unsigned)u0 < 6u) && ((unsigned)u1 < 6u)
                       && ((unsigned)vvv < 71u);
            lidx1[j] = u1 * 72 + vvv;
            lidx0[j] = fastp ? (u0 * 72 + vvv) : -1;
        }
    }

    if (tid < 128) {                      // zero K-pad [144,160)
        short8 z = {0,0,0,0,0,0,0,0};
        *(short8*)&S[(tid >> 1) * LDK + 144 + (tid & 1) * 8] = z;
    }

    f32x4 acc[4][2];
    #pragma unroll
    for (int i = 0; i < 4; ++i)
        #pragma unroll
        for (int j = 0; j < 2; ++j)
            acc[i][j] = (f32x4){0.f, 0.f, 0.f, 0.f};

    // ---- sample half (channel base h*8, S parity par) from XW ----
    auto sample_h = [&](int h, int par) {
        #pragma unroll
        for (int j = 0; j < 3; ++j) {
            int s = tid + j * 256;
            if (s < 576) {
                int k = s >> 6, p = s & 63;
                float va[8];
                float wa0 = wA0[j], wb0 = wB0[j], wa1 = wA1[j], wb1 = wB1[j];
                if (lidx0[j] >= 0) {
                    int l0 = lidx0[j], l1 = lidx1[j];
                    #pragma unroll
                    for (int ci = 0; ci < 8; ++ci) {
                        const float* bp = &XW[ci * 432];
                        float a0 = bp[l0], a1 = bp[l0 + 1];
                        float b0 = bp[l1], b1 = bp[l1 + 1];
                        va[ci] = wa0 * a0 + wb0 * a1 + wa1 * b0 + wb1 * b1;
                    }
                } else {
                    #pragma unroll
                    for (int ci = 0; ci < 8; ++ci) {
                        const char* pc = (const char*)(xb + (size_t)(h * 8 + ci) * HW);
                        f32x2 A  = *(const f32x2a*)(pc + moff[j][0]);
                        f32x2 Bv = *(const f32x2a*)(pc + moff[j][1]);
                        va[ci] = wa0 * A.x + wb0 * A.y + wa1 * Bv.x + wb1 * Bv.y;
                    }
                }
                short8 sv;
                #pragma unroll
                for (int ci = 0; ci < 8; ++ci) sv[ci] = (short)f2bf(va[ci]);
                *(short8*)&S[p * LDK + k * 16 + par * 8] = sv;
            }
        }
    };

    auto mfma_step = [&](int c) {
        #pragma unroll
        for (int ks = 0; ks < 5; ++ks) {
            short8 a[4];
            #pragma unroll
            for (int of = 0; of < 4; ++of) {
                int o = oh + of * 16 + row16;
                a[of] = *(const short8*)(wbf + o * WBF_COLS + c * 160 + ks * 32 + kq * 8);
            }
            #pragma unroll
            for (int pf = 0; pf < 2; ++pf) {
                int p = ph + pf * 16 + row16;
                short8 bfr = *(const short8*)&S[p * LDK + ks * 32 + kq * 8];
                #pragma unroll
                for (int of = 0; of < 4; ++of)
                    acc[of][pf] = __builtin_amdgcn_mfma_f32_16x16x32_bf16(
                        a[of], bfr, acc[of][pf], 0, 0, 0);
            }
        }
    };

    // ---- pipelined main loop, uniform chunk order (no stagger) ----
    #pragma unroll 1
    for (int c = 0; c < 4; ++c) {
        regwrite();                         // XW <- half 2c (readers synced)
        regload(2 * c + 1);                 // next half in flight
        __syncthreads();
        sample_h(2 * c, 0);
        __syncthreads();                    // XW reads done
        regwrite();                         // XW <- half 2c+1
        if (c < 3) regload(2 * c + 2);
        __syncthreads();
        sample_h(2 * c + 1, 1);
        __syncthreads();                    // S complete for chunk c
        mfma_step(c);
    }

    // ---- store: C/D layout col(px)=lane&15, row(o)=(lane>>4)*4+r ----
    #pragma unroll
    for (int of = 0; of < 4; ++of) {
        #pragma unroll
        for (int r = 0; r < 4; ++r) {
            int o = oh + of * 16 + kq * 4 + r;
            float* orow = out + ((b * COUT + o) * H + ho) * W;
            #pragma unroll
            for (int pf = 0; pf < 2; ++pf) {
                int wo = wo0 + ph + pf * 16 + row16;
                orow[wo] = acc[of][pf][r];
            }
        }
    }
}

// ---------------------------------------------------------------------------
extern "C" void kernel_launch(void* const* d_in, const int* in_sizes, int n_in,
                              void* d_out, int out_size, void* d_ws, size_t ws_size,
                              hipStream_t stream)
{
    const float* x      = (const float*)d_in[0];
    const float* w_off  = (const float*)d_in[1];
    const float* b_off  = (const float*)d_in[2];
    const float* w_mask = (const float*)d_in[3];
    const float* b_mask = (const float*)d_in[4];
    const float* weight = (const float*)d_in[5];
    float* out   = (float*)d_out;

    float* offs  = (float*)d_ws;
    float* maskb = offs + OFFS_SZ;
    float* bcat  = maskb + MASK_SZ;
    short* wbf   = (short*)(bcat + 32);
    float* wtap2 = bcat + 32 + WBF_SHORTS / 2;

    prep_kernel<<<dim3((WTAP2_SZ + 255) / 256), 256, 0, stream>>>(
        w_off, b_off, w_mask, b_mask, wtap2, bcat);
    prep_wbf<<<dim3((WBF_SHORTS + 255) / 256), 256, 0, stream>>>(weight, wbf);
    offmask5_kernel<<<dim3(1024), 256, 0, stream>>>(x, wtap2, bcat, offs, maskb);
    deform6_kernel<<<dim3(1024), 256, 0, stream>>>(x, offs, maskb, wbf, out);
}